// Round 1
// baseline (1384.333 us; speedup 1.0000x reference)
//
#include <hip/hip_runtime.h>
#include <cstdint>
#include <cstddef>

typedef __bf16 bf16;
typedef __bf16 bf16x8 __attribute__((ext_vector_type(8)));
typedef float f32x4 __attribute__((ext_vector_type(4)));

// ---------------------------------------------------------------- weight cvt
// qkv_w 442368 | proj_w 147456 | fc1_w 589824 | fc2_w 589824 = 1769472 total
__global__ __launch_bounds__(256) void k_cvtw(
    const float* __restrict__ w0, const float* __restrict__ w1,
    const float* __restrict__ w2, const float* __restrict__ w3,
    bf16* __restrict__ o)
{
    int i = blockIdx.x * 256 + threadIdx.x;
    float v;
    if (i < 442368)       v = w0[i];
    else if (i < 589824)  v = w1[i - 442368];
    else if (i < 1179648) v = w2[i - 589824];
    else                  v = w3[i - 1179648];
    o[i] = (bf16)v;
}

// ---------------------------------------------------------------- layernorm
__device__ __forceinline__ void ln_stats(const float* __restrict__ xp, int lane,
                                         float v[6], float& mean, float& rstd)
{
    float s = 0.f, ss = 0.f;
    #pragma unroll
    for (int j = 0; j < 6; ++j) {
        v[j] = xp[j * 64 + lane];
        s += v[j]; ss += v[j] * v[j];
    }
    #pragma unroll
    for (int o = 32; o; o >>= 1) { s += __shfl_xor(s, o); ss += __shfl_xor(ss, o); }
    mean = s * (1.f / 384.f);
    float var = ss * (1.f / 384.f) - mean * mean;
    rstd = rsqrtf(var + 1e-5f);
}

// LN1 + cyclic shift(-3,-3) + window partition -> ywin (B*nW, 49, 384) bf16
__global__ __launch_bounds__(256) void k_ln1(
    const float* __restrict__ x, const float* __restrict__ g,
    const float* __restrict__ b, bf16* __restrict__ ywin)
{
    int wv = threadIdx.x >> 6, lane = threadIdx.x & 63;
    int tok = blockIdx.x * 4 + wv;            // 0..100351
    float v[6], mean, rstd;
    ln_stats(x + (size_t)tok * 384, lane, v, mean, rstd);
    int bi = tok / 3136, l = tok - bi * 3136;
    int h = l / 56, w = l - h * 56;
    int hs = h + 53; if (hs >= 56) hs -= 56;  // (h-3) mod 56
    int ws = w + 53; if (ws >= 56) ws -= 56;
    int m = (bi * 64 + (hs / 7) * 8 + (ws / 7)) * 49 + (hs % 7) * 7 + (ws % 7);
    bf16* op = ywin + (size_t)m * 384;
    #pragma unroll
    for (int j = 0; j < 6; ++j) {
        int ch = j * 64 + lane;
        op[ch] = (bf16)((v[j] - mean) * rstd * g[ch] + b[ch]);
    }
}

// plain LN2: x2 (fp32, in d_out) -> y2 bf16
__global__ __launch_bounds__(256) void k_ln2(
    const float* __restrict__ x, const float* __restrict__ g,
    const float* __restrict__ b, bf16* __restrict__ y)
{
    int wv = threadIdx.x >> 6, lane = threadIdx.x & 63;
    int tok = blockIdx.x * 4 + wv;
    float v[6], mean, rstd;
    ln_stats(x + (size_t)tok * 384, lane, v, mean, rstd);
    bf16* op = y + (size_t)tok * 384;
    #pragma unroll
    for (int j = 0; j < 6; ++j) {
        int ch = j * 64 + lane;
        op[ch] = (bf16)((v[j] - mean) * rstd * g[ch] + b[ch]);
    }
}

// ---------------------------------------------------------------- GEMM
// C[M,N] = A[M,K] * Bt[N,K]^T (+ epilogue). 128x128 tile, BK=32, 4 waves.
// EPI: 0 = qkv (bias, fold q-scale, bf16 out, ld=N)
//      1 = proj (bias + window-reverse + unshift + residual add, fp32 out)
//      2 = fc1 (bias + exact GELU, bf16 out)
//      3 = fc2 (bias + accumulate into fp32 out)
template<int EPI>
__global__ __launch_bounds__(256) void k_gemm(
    const bf16* __restrict__ A, const bf16* __restrict__ Bt,
    const float* __restrict__ bias, const float* __restrict__ resid,
    void* __restrict__ out, int N, int K, int nbn)
{
    __shared__ bf16 As[128 * 32];
    __shared__ bf16 Bs[128 * 32];

    // XCD-aware swizzle (all grids divisible by 8 -> bijective)
    int nwg = gridDim.x;
    int bid = blockIdx.x;
    int swz = (bid & 7) * (nwg >> 3) + (bid >> 3);
    int bm = swz / nbn, bn = swz % nbn;

    int tid  = threadIdx.x;
    int lane = tid & 63;
    int wv   = tid >> 6;
    int wr = wv >> 1, wc = wv & 1;
    int lr = lane & 15, lg = lane >> 4;

    // staging: 512 16B-chunks per tile; thread t handles chunks t and t+256
    // chunk c: row=c>>2, seg=c&3; LDS slot = seg ^ ((row>>1)&3)  (bank swizzle)
    int r1 = tid >> 2;
    int sl = (tid & 3) ^ ((tid >> 3) & 3);
    int la1 = r1 * 32 + sl * 8;            // elements
    int la2 = la1 + 64 * 32;
    const bf16* a1 = A  + (size_t)(bm * 128 + r1) * K + (tid & 3) * 8;
    const bf16* b1 = Bt + (size_t)(bn * 128 + r1) * K + (tid & 3) * 8;
    const bf16* a2 = a1 + (size_t)64 * K;
    const bf16* b2 = b1 + (size_t)64 * K;

    f32x4 acc[4][4] = {};

    uint4 va1 = *(const uint4*)(a1);
    uint4 va2 = *(const uint4*)(a2);
    uint4 vb1 = *(const uint4*)(b1);
    uint4 vb2 = *(const uint4*)(b2);

    for (int k0 = 0; k0 < K; k0 += 32) {
        __syncthreads();
        *(uint4*)&As[la1] = va1;  *(uint4*)&As[la2] = va2;
        *(uint4*)&Bs[la1] = vb1;  *(uint4*)&Bs[la2] = vb2;
        __syncthreads();
        if (k0 + 32 < K) {
            va1 = *(const uint4*)(a1 + k0 + 32);
            va2 = *(const uint4*)(a2 + k0 + 32);
            vb1 = *(const uint4*)(b1 + k0 + 32);
            vb2 = *(const uint4*)(b2 + k0 + 32);
        }
        bf16x8 af[4], bfr[4];
        #pragma unroll
        for (int i = 0; i < 4; ++i) {
            int ra = wr * 64 + i * 16 + lr;
            af[i]  = *(const bf16x8*)&As[ra * 32 + ((lg ^ ((ra >> 1) & 3)) << 3)];
            int rb = wc * 64 + i * 16 + lr;
            bfr[i] = *(const bf16x8*)&Bs[rb * 32 + ((lg ^ ((rb >> 1) & 3)) << 3)];
        }
        #pragma unroll
        for (int mi = 0; mi < 4; ++mi)
            #pragma unroll
            for (int ni = 0; ni < 4; ++ni)
                acc[mi][ni] = __builtin_amdgcn_mfma_f32_16x16x32_bf16(
                    af[mi], bfr[ni], acc[mi][ni], 0, 0, 0);
    }

    int row0 = bm * 128 + wr * 64;
    int col0 = bn * 128 + wc * 64;
    #pragma unroll
    for (int mi = 0; mi < 4; ++mi)
    #pragma unroll
    for (int ni = 0; ni < 4; ++ni)
    #pragma unroll
    for (int r = 0; r < 4; ++r) {
        int gr = row0 + mi * 16 + lg * 4 + r;   // C/D: row=(lane>>4)*4+reg
        int gc = col0 + ni * 16 + lr;           //      col=lane&15
        float v = acc[mi][ni][r] + bias[gc];
        if constexpr (EPI == 0) {
            if (gc < 384) v *= 0.17677669529663687f;   // d^-0.5 folded into q
            ((bf16*)out)[(size_t)gr * N + gc] = (bf16)v;
        } else if constexpr (EPI == 1) {
            int bi = gr / 3136, rem = gr - bi * 3136;
            int win = rem / 49, pos = rem - win * 49;
            int hs = (win >> 3) * 7 + pos / 7;
            int ws = (win & 7) * 7 + pos % 7;
            hs += 3; if (hs >= 56) hs -= 56;   // reverse shift
            ws += 3; if (ws >= 56) ws -= 56;
            size_t oi = ((size_t)bi * 3136 + hs * 56 + ws) * 384 + gc;
            ((float*)out)[oi] = resid[oi] + v;
        } else if constexpr (EPI == 2) {
            float ge = 0.5f * v * (1.f + erff(v * 0.70710678118654752f));
            ((bf16*)out)[(size_t)gr * N + gc] = (bf16)ge;
        } else {
            size_t oi = (size_t)gr * 384 + gc;
            ((float*)out)[oi] += v;
        }
    }
}

// ---------------------------------------------------------------- attention
// one wave per (window, head); fp32 VALU; bias + shift-mask computed inline
__global__ __launch_bounds__(64) void k_attn(
    const bf16* __restrict__ qkv, const float* __restrict__ rpb,
    bf16* __restrict__ outb)
{
    __shared__ float k_s[49 * 32];
    __shared__ float v_s[49 * 32];
    __shared__ float s_l[49 * 51];
    __shared__ float bias_s[169];
    __shared__ int   lab_s[49];

    int head   = blockIdx.x % 12;
    int window = blockIdx.x / 12;
    int lane   = threadIdx.x;
    size_t base = (size_t)window * 49 * 1152 + head * 32;

    // stage K, V (bf16 -> fp32 LDS)
    for (int c = lane; c < 196; c += 64) {
        int pos = c >> 2, d0 = (c & 3) << 3;
        bf16x8 kv = *(const bf16x8*)(qkv + base + 384 + (size_t)pos * 1152 + d0);
        bf16x8 vv = *(const bf16x8*)(qkv + base + 768 + (size_t)pos * 1152 + d0);
        #pragma unroll
        for (int t = 0; t < 8; ++t) {
            k_s[pos * 32 + d0 + t] = (float)kv[t];
            v_s[pos * 32 + d0 + t] = (float)vv[t];
        }
    }
    for (int idx = lane; idx < 169; idx += 64) bias_s[idx] = rpb[idx * 12 + head];
    {
        int win = window & 63;
        int wh = win >> 3, ww = win & 7;
        if (lane < 49) {
            int hs = wh * 7 + lane / 7, ws = ww * 7 + lane % 7;
            int rr = hs < 49 ? 0 : (hs < 53 ? 1 : 2);
            int cc = ws < 49 ? 0 : (ws < 53 ? 1 : 2);
            lab_s[lane] = rr * 3 + cc;
        }
    }
    __syncthreads();
    if (lane >= 49) return;

    int row = lane;
    float qr[32];
    {
        const bf16* qp = qkv + base + (size_t)row * 1152;  // q already scaled
        #pragma unroll
        for (int d0 = 0; d0 < 32; d0 += 8) {
            bf16x8 qv = *(const bf16x8*)(qp + d0);
            #pragma unroll
            for (int t = 0; t < 8; ++t) qr[d0 + t] = (float)qv[t];
        }
    }
    int r0 = row / 7, c0 = row - r0 * 7;
    int lab0 = lab_s[row];
    float* srow = &s_l[row * 51];

    float mx = -1e30f;
    for (int j = 0; j < 49; ++j) {
        const float* kp = &k_s[j * 32];
        float d0 = 0.f, d1 = 0.f, d2 = 0.f, d3 = 0.f;
        #pragma unroll
        for (int d = 0; d < 32; d += 4) {
            d0 += qr[d] * kp[d];     d1 += qr[d + 1] * kp[d + 1];
            d2 += qr[d + 2] * kp[d + 2]; d3 += qr[d + 3] * kp[d + 3];
        }
        float dot = (d0 + d1) + (d2 + d3);
        int jr = j / 7, jc = j - jr * 7;
        dot += bias_s[(r0 - jr + 6) * 13 + (c0 - jc + 6)];
        if (lab0 != lab_s[j]) dot -= 100.f;
        srow[j] = dot;
        mx = fmaxf(mx, dot);
    }
    float sum = 0.f;
    for (int j = 0; j < 49; ++j) {
        float e = __expf(srow[j] - mx);
        srow[j] = e; sum += e;
    }
    float rs = 1.f / sum;

    float o[32];
    #pragma unroll
    for (int d = 0; d < 32; ++d) o[d] = 0.f;
    for (int j = 0; j < 49; ++j) {
        float p = srow[j];
        const float* vp = &v_s[j * 32];
        #pragma unroll
        for (int d = 0; d < 32; ++d) o[d] += p * vp[d];
    }
    bf16* op = outb + (size_t)(window * 49 + row) * 384 + head * 32;
    #pragma unroll
    for (int d0 = 0; d0 < 32; d0 += 8) {
        bf16x8 ov;
        #pragma unroll
        for (int t = 0; t < 8; ++t) ov[t] = (bf16)(o[d0 + t] * rs);
        *(bf16x8*)(op + d0) = ov;
    }
}

// ---------------------------------------------------------------- launch
extern "C" void kernel_launch(void* const* d_in, const int* in_sizes, int n_in,
                              void* d_out, int out_size, void* d_ws, size_t ws_size,
                              hipStream_t stream)
{
    const float* x     = (const float*)d_in[0];
    const float* n1g   = (const float*)d_in[1];
    const float* n1b   = (const float*)d_in[2];
    const float* qkvw  = (const float*)d_in[3];
    const float* qkvb  = (const float*)d_in[4];
    const float* rpb   = (const float*)d_in[5];
    const float* projw = (const float*)d_in[6];
    const float* projb = (const float*)d_in[7];
    const float* n2g   = (const float*)d_in[8];
    const float* n2b   = (const float*)d_in[9];
    const float* fc1w  = (const float*)d_in[10];
    const float* fc1b  = (const float*)d_in[11];
    const float* fc2w  = (const float*)d_in[12];
    const float* fc2b  = (const float*)d_in[13];
    float* out = (float*)d_out;

    char* ws = (char*)d_ws;
    bf16* Wq   = (bf16*)(ws);                 // 442368 el (all 4 weights contiguous)
    bf16* Wp   = (bf16*)(ws + 884736);
    bf16* W1   = (bf16*)(ws + 1179648);
    bf16* W2   = (bf16*)(ws + 2359296);
    bf16* ywin = (bf16*)(ws + 3538944);       // 100352*384 bf16
    bf16* qkv  = (bf16*)(ws + 80609280);      // 100352*1152 bf16
    bf16* attn = (bf16*)(ws + 311820288);     // 100352*384 bf16
    bf16* hbuf = (bf16*)(ws + 80609280);      // reuse qkv+attn: 100352*1536 bf16
    bf16* y2   = ywin;                        // reuse after qkv gemm
    // total ws use: 388,890,624 bytes

    k_cvtw<<<6912, 256, 0, stream>>>(qkvw, projw, fc1w, fc2w, Wq);
    k_ln1<<<25088, 256, 0, stream>>>(x, n1g, n1b, ywin);
    k_gemm<0><<<784 * 9, 256, 0, stream>>>(ywin, Wq, qkvb, nullptr, qkv, 1152, 384, 9);
    k_attn<<<24576, 64, 0, stream>>>(qkv, rpb, attn);
    k_gemm<1><<<784 * 3, 256, 0, stream>>>(attn, Wp, projb, x, out, 384, 384, 3);
    k_ln2<<<25088, 256, 0, stream>>>(out, n2g, n2b, y2);
    k_gemm<2><<<784 * 12, 256, 0, stream>>>(y2, W1, fc1b, nullptr, hbuf, 1536, 384, 12);
    k_gemm<3><<<784 * 3, 256, 0, stream>>>(hbuf, W2, fc2b, nullptr, out, 384, 1536, 3);
}

// Round 3
// 1229.191 us; speedup vs baseline: 1.1262x; 1.1262x over previous
//
#include <hip/hip_runtime.h>
#include <cstdint>
#include <cstddef>

typedef __bf16 bf16;
typedef __bf16 bf16x8 __attribute__((ext_vector_type(8)));
typedef float f32x4 __attribute__((ext_vector_type(4)));
typedef unsigned int u32;

__device__ __forceinline__ u32 pk(float a, float b) {
    u32 ua = __builtin_bit_cast(unsigned short, (bf16)a);
    u32 ub = __builtin_bit_cast(unsigned short, (bf16)b);
    return (ub << 16) | ua;
}

// async global->LDS, 16B per lane; LDS dest = wave-uniform base + lane*16
__device__ __forceinline__ void gld16(void* l, const void* g) {
    __builtin_amdgcn_global_load_lds(
        (const __attribute__((address_space(1))) void*)(size_t)g,
        (__attribute__((address_space(3))) void*)l, 16, 0, 0);
}

// ---------------------------------------------------------------- weight cvt
// qkv_w 442368 | proj_w 147456 | fc1_w 589824 | fc2_w 589824 = 1769472 total
__global__ __launch_bounds__(256) void k_cvtw(
    const float* __restrict__ w0, const float* __restrict__ w1,
    const float* __restrict__ w2, const float* __restrict__ w3,
    bf16* __restrict__ o)
{
    int i = blockIdx.x * 256 + threadIdx.x;
    float v;
    if (i < 442368)       v = w0[i];
    else if (i < 589824)  v = w1[i - 442368];
    else if (i < 1179648) v = w2[i - 589824];
    else                  v = w3[i - 1179648];
    o[i] = (bf16)v;
}

// ---------------------------------------------------------------- fused bias
// fusedT[type][head][i][j], type = (wh==7)*2 + (ww==7); log2e folded in.
// j>=49 -> -1e30 (kills padded K columns); i>=49 -> 0 (rows discarded).
__global__ __launch_bounds__(256) void k_bias(
    const float* __restrict__ rpb, float* __restrict__ ft)
{
    int t = blockIdx.x;                  // 0..47 = type*12+head
    int type = t / 12, head = t - (t / 12) * 12;
    for (int e = threadIdx.x; e < 4096; e += 256) {
        int i = e >> 6, j = e & 63;
        float v;
        if (j >= 49) v = -1e30f;
        else if (i >= 49) v = 0.f;
        else {
            int ri = i / 7, ci = i - ri * 7, rj = j / 7, cj = j - rj * 7;
            v = rpb[((ri - rj + 6) * 13 + (ci - cj + 6)) * 12 + head] * 1.4426950408889634f;
            int li = 0, lj = 0;
            if (type & 2) { li += (ri < 4) ? 3 : 6; lj += (rj < 4) ? 3 : 6; }
            if (type & 1) { li += (ci < 4) ? 1 : 2; lj += (cj < 4) ? 1 : 2; }
            if (li != lj) v -= 144.26950408889634f;   // -100 * log2e
        }
        ft[(size_t)t * 4096 + e] = v;
    }
}

// ---------------------------------------------------------------- layernorm
// LN1 + cyclic shift(-3,-3) + window partition -> ywin (B*nW, 49, 384) bf16
__global__ __launch_bounds__(256) void k_ln1(
    const float* __restrict__ x, const float* __restrict__ g,
    const float* __restrict__ b, bf16* __restrict__ ywin)
{
    int wv = threadIdx.x >> 6, lane = threadIdx.x & 63;
    int tok = blockIdx.x * 4 + wv;            // 0..100351
    const float2* xp = (const float2*)(x + (size_t)tok * 384);
    float2 v[3];
    float s = 0.f, ss = 0.f;
    #pragma unroll
    for (int j = 0; j < 3; ++j) {
        v[j] = xp[j * 64 + lane];
        s += v[j].x + v[j].y; ss += v[j].x * v[j].x + v[j].y * v[j].y;
    }
    #pragma unroll
    for (int o = 32; o; o >>= 1) { s += __shfl_xor(s, o); ss += __shfl_xor(ss, o); }
    float mean = s * (1.f / 384.f);
    float rstd = rsqrtf(ss * (1.f / 384.f) - mean * mean + 1e-5f);
    int bi = tok / 3136, l = tok - bi * 3136;
    int h = l / 56, w = l - h * 56;
    int hs = h + 53; if (hs >= 56) hs -= 56;  // (h-3) mod 56
    int ws = w + 53; if (ws >= 56) ws -= 56;
    int m = (bi * 64 + (hs / 7) * 8 + (ws / 7)) * 49 + (hs % 7) * 7 + (ws % 7);
    u32* op = (u32*)(ywin + (size_t)m * 384);
    const float2* g2 = (const float2*)g;
    const float2* b2 = (const float2*)b;
    #pragma unroll
    for (int j = 0; j < 3; ++j) {
        int c2 = j * 64 + lane;
        float2 gg = g2[c2], bb = b2[c2];
        op[c2] = pk((v[j].x - mean) * rstd * gg.x + bb.x,
                    (v[j].y - mean) * rstd * gg.y + bb.y);
    }
}

// plain LN2: x2 (fp32, in d_out) -> y2 bf16
__global__ __launch_bounds__(256) void k_ln2(
    const float* __restrict__ x, const float* __restrict__ g,
    const float* __restrict__ b, bf16* __restrict__ y)
{
    int wv = threadIdx.x >> 6, lane = threadIdx.x & 63;
    int tok = blockIdx.x * 4 + wv;
    const float2* xp = (const float2*)(x + (size_t)tok * 384);
    float2 v[3];
    float s = 0.f, ss = 0.f;
    #pragma unroll
    for (int j = 0; j < 3; ++j) {
        v[j] = xp[j * 64 + lane];
        s += v[j].x + v[j].y; ss += v[j].x * v[j].x + v[j].y * v[j].y;
    }
    #pragma unroll
    for (int o = 32; o; o >>= 1) { s += __shfl_xor(s, o); ss += __shfl_xor(ss, o); }
    float mean = s * (1.f / 384.f);
    float rstd = rsqrtf(ss * (1.f / 384.f) - mean * mean + 1e-5f);
    u32* op = (u32*)(y + (size_t)tok * 384);
    const float2* g2 = (const float2*)g;
    const float2* b2 = (const float2*)b;
    #pragma unroll
    for (int j = 0; j < 3; ++j) {
        int c2 = j * 64 + lane;
        float2 gg = g2[c2], bb = b2[c2];
        op[c2] = pk((v[j].x - mean) * rstd * gg.x + bb.x,
                    (v[j].y - mean) * rstd * gg.y + bb.y);
    }
}

// ---------------------------------------------------------------- GEMM
// C[M,N] = A[M,K] * Bt[N,K]^T (+ epilogue). 128x128 tile, BK=32, 4 waves.
// global_load_lds staging: LDS linear, bank-XOR pre-applied on global src.
// EPI: 0 = qkv (bias, fold q-scale*log2e, bf16 out)
//      1 = proj (bias + window-reverse + unshift + residual add, fp32 out)
//      2 = fc1 (bias + exact GELU, bf16 out)
//      3 = fc2 (bias + accumulate into fp32 out)
template<int EPI>
__global__ __launch_bounds__(256) void k_gemm(
    const bf16* __restrict__ A, const bf16* __restrict__ Bt,
    const float* __restrict__ bias, const float* __restrict__ resid,
    void* __restrict__ out, int N, int K, int nbn)
{
    __shared__ bf16 As[128 * 32];
    __shared__ bf16 Bs[128 * 32];

    int nwg = gridDim.x;
    int bid = blockIdx.x;
    int swz = (bid & 7) * (nwg >> 3) + (bid >> 3);   // grids all %8==0
    int bm = swz / nbn, bn = swz % nbn;

    int tid  = threadIdx.x;
    int lane = tid & 63;
    int wv   = tid >> 6;
    int wr = wv >> 1, wc = wv & 1;
    int lr = lane & 15, lg = lane >> 4;

    // wave wv stages rows [32wv,32wv+32): 2 calls of 16 rows x 64B for A, B.
    // LDS[row][slot] = G[row][slot ^ ((row>>1)&3)]
    int rowL = wv * 32 + (lane >> 2);
    int seg  = (lane & 3) ^ ((rowL >> 1) & 3);
    const bf16* ga0 = A  + (size_t)(bm * 128 + rowL) * K + seg * 8;
    const bf16* gb0 = Bt + (size_t)(bn * 128 + rowL) * K + seg * 8;
    const bf16* ga1 = ga0 + (size_t)16 * K;           // x((row+16)) == x(row)
    const bf16* gb1 = gb0 + (size_t)16 * K;
    bf16* lA0 = &As[(wv * 32) * 32];
    bf16* lA1 = &As[(wv * 32 + 16) * 32];
    bf16* lB0 = &Bs[(wv * 32) * 32];
    bf16* lB1 = &Bs[(wv * 32 + 16) * 32];

    f32x4 acc[4][4] = {};

    for (int k0 = 0; k0 < K; k0 += 32) {
        gld16(lA0, ga0 + k0); gld16(lA1, ga1 + k0);
        gld16(lB0, gb0 + k0); gld16(lB1, gb1 + k0);
        __syncthreads();
        bf16x8 af[4], bfr[4];
        #pragma unroll
        for (int i = 0; i < 4; ++i) {
            int ra = wr * 64 + i * 16 + lr;
            af[i]  = *(const bf16x8*)&As[ra * 32 + ((lg ^ ((ra >> 1) & 3)) << 3)];
            int rb = wc * 64 + i * 16 + lr;
            bfr[i] = *(const bf16x8*)&Bs[rb * 32 + ((lg ^ ((rb >> 1) & 3)) << 3)];
        }
        #pragma unroll
        for (int mi = 0; mi < 4; ++mi)
            #pragma unroll
            for (int ni = 0; ni < 4; ++ni)
                acc[mi][ni] = __builtin_amdgcn_mfma_f32_16x16x32_bf16(
                    af[mi], bfr[ni], acc[mi][ni], 0, 0, 0);
        __syncthreads();
    }

    int row0 = bm * 128 + wr * 64;
    int col0 = bn * 128 + wc * 64;
    #pragma unroll
    for (int mi = 0; mi < 4; ++mi)
    #pragma unroll
    for (int ni = 0; ni < 4; ++ni)
    #pragma unroll
    for (int r = 0; r < 4; ++r) {
        int gr = row0 + mi * 16 + lg * 4 + r;   // C/D: row=(lane>>4)*4+reg
        int gc = col0 + ni * 16 + lr;           //      col=lane&15
        float v = acc[mi][ni][r] + bias[gc];
        if constexpr (EPI == 0) {
            if (gc < 384) v *= 0.25498226244716875f;   // d^-0.5 * log2(e)
            ((bf16*)out)[(size_t)gr * N + gc] = (bf16)v;
        } else if constexpr (EPI == 1) {
            int bi = gr / 3136, rem = gr - bi * 3136;
            int win = rem / 49, pos = rem - win * 49;
            int hs = (win >> 3) * 7 + pos / 7;
            int ws = (win & 7) * 7 + pos % 7;
            hs += 3; if (hs >= 56) hs -= 56;   // reverse shift
            ws += 3; if (ws >= 56) ws -= 56;
            size_t oi = ((size_t)bi * 3136 + hs * 56 + ws) * 384 + gc;
            ((float*)out)[oi] = resid[oi] + v;
        } else if constexpr (EPI == 2) {
            float ge = 0.5f * v * (1.f + erff(v * 0.70710678118654752f));
            ((bf16*)out)[(size_t)gr * N + gc] = (bf16)ge;
        } else {
            size_t oi = (size_t)gr * 384 + gc;
            ((float*)out)[oi] += v;
        }
    }
}

// ---------------------------------------------------------------- attention
// 4 waves/block = 4 heads of one window. Per wave:
//   S^T = mfma(K,Q)  (C/D verified: j=(mj,lg*4+r), i=(ni,lr))
//   += fusedT[type][head][i][j] float4 loads (bias+mask+pad, log2e domain)
//   softmax over j: per-lane 16 + shfl_xor(16,32); 1/l folded into P
//   P -> per-wave swizzled LDS [i][j] (write is the transpose), read A-frags
//   V -> per-wave transposed+swizzled LDS (pad rows zeroed), read B-frags
//   O = P.V via mfma; store rows i<49
__global__ __launch_bounds__(256, 3) void k_attn(
    const bf16* __restrict__ qkv, const float* __restrict__ fusedT,
    bf16* __restrict__ outb)
{
    __shared__ bf16 vt[4][32 * 64];
    __shared__ bf16 pl[4][64 * 64];

    int bid = blockIdx.x;
    int swz = (bid & 7) * (6144 >> 3) + (bid >> 3);
    int window = swz / 3;
    int wv = threadIdx.x >> 6, lane = threadIdx.x & 63;
    int head = (swz - window * 3) * 4 + wv;
    int lr = lane & 15, lg = lane >> 4;

    size_t base = (size_t)window * 49 * 1152 + head * 32;
    const bf16* Qp = qkv + base;
    const bf16* Kp = qkv + base + 384;
    const bf16* Vp = qkv + base + 768;

    // ---- stage V^T (32 x 64, 16B-chunk XOR swizzle), zero pad rows first
    bf16* vts = vt[wv];
    #pragma unroll
    for (int t0 = 0; t0 < 8; ++t0) {
        int t = t0 * 64 + lane;            // 512 tasks: d x pos(48..63)
        int d = t >> 4, pos = 48 + (t & 15);
        vts[d * 64 + ((((pos >> 3) ^ (d & 7)) << 3) | (pos & 7))] = (bf16)0.f;
    }
    #pragma unroll
    for (int t0 = 0; t0 < 4; ++t0) {
        int t = t0 * 64 + lane;            // 196 tasks: pos x 4 d-chunks
        if (t < 196) {
            int pos = t >> 2, c8 = (t & 3) << 3;
            bf16x8 vv = *(const bf16x8*)(Vp + (size_t)pos * 1152 + c8);
            #pragma unroll
            for (int u = 0; u < 8; ++u) {
                int d = c8 + u;
                vts[d * 64 + ((((pos >> 3) ^ (d & 7)) << 3) | (pos & 7))] = vv[u];
            }
        }
    }

    // ---- Q/K fragments straight from global (rows clamped to 48)
    bf16x8 kf[4], qf[4];
    #pragma unroll
    for (int t = 0; t < 4; ++t) {
        int row = t * 16 + lr; row = row > 48 ? 48 : row;
        kf[t] = *(const bf16x8*)(Kp + (size_t)row * 1152 + lg * 8);
        qf[t] = *(const bf16x8*)(Qp + (size_t)row * 1152 + lg * 8);
    }
    f32x4 st[4][4];
    #pragma unroll
    for (int a = 0; a < 4; ++a)
        #pragma unroll
        for (int c = 0; c < 4; ++c) st[a][c] = f32x4{0.f, 0.f, 0.f, 0.f};
    #pragma unroll
    for (int mj = 0; mj < 4; ++mj)
        #pragma unroll
        for (int ni = 0; ni < 4; ++ni)
            st[mj][ni] = __builtin_amdgcn_mfma_f32_16x16x32_bf16(
                kf[mj], qf[ni], st[mj][ni], 0, 0, 0);

    // ---- bias + mask + padding (already *log2e)
    int wtype = (((window & 63) >= 56) ? 2 : 0) | (((window & 7) == 7) ? 1 : 0);
    const float* bt = fusedT + ((size_t)(wtype * 12 + head) << 12);
    #pragma unroll
    for (int ni = 0; ni < 4; ++ni)
        #pragma unroll
        for (int mj = 0; mj < 4; ++mj) {
            f32x4 bv = *(const f32x4*)(bt + (ni * 16 + lr) * 64 + mj * 16 + lg * 4);
            st[mj][ni] += bv;
        }

    // ---- softmax over j (per output column i), exp2 domain
    #pragma unroll
    for (int ni = 0; ni < 4; ++ni) {
        float mx = -1e30f;
        #pragma unroll
        for (int mj = 0; mj < 4; ++mj)
            mx = fmaxf(mx, fmaxf(fmaxf(st[mj][ni][0], st[mj][ni][1]),
                                 fmaxf(st[mj][ni][2], st[mj][ni][3])));
        mx = fmaxf(mx, __shfl_xor(mx, 16));
        mx = fmaxf(mx, __shfl_xor(mx, 32));
        float l = 0.f;
        #pragma unroll
        for (int mj = 0; mj < 4; ++mj)
            #pragma unroll
            for (int r = 0; r < 4; ++r) {
                float p = exp2f(st[mj][ni][r] - mx);
                st[mj][ni][r] = p; l += p;
            }
        l += __shfl_xor(l, 16);
        l += __shfl_xor(l, 32);
        float rl = 1.f / l;
        #pragma unroll
        for (int mj = 0; mj < 4; ++mj)
            #pragma unroll
            for (int r = 0; r < 4; ++r) st[mj][ni][r] *= rl;
    }

    // ---- P^T(acc) -> row-major P in LDS (swizzled); pairs along j are u32
    bf16* plw = pl[wv];
    #pragma unroll
    for (int mj = 0; mj < 4; ++mj)
        #pragma unroll
        for (int ni = 0; ni < 4; ++ni)
            #pragma unroll
            for (int hh = 0; hh < 2; ++hh) {
                u32 w = pk(st[mj][ni][hh * 2], st[mj][ni][hh * 2 + 1]);
                int j = mj * 16 + lg * 4 + hh * 2;
                int i = ni * 16 + lr;
                *(u32*)&plw[i * 64 + (((j >> 3) ^ (lr & 7)) << 3) + (j & 7)] = w;
            }

    bf16x8 pa[4][2], vf[2][2];
    #pragma unroll
    for (int mi = 0; mi < 4; ++mi)
        #pragma unroll
        for (int kk = 0; kk < 2; ++kk)
            pa[mi][kk] = *(const bf16x8*)&plw[(mi * 16 + lr) * 64 +
                                              (((kk * 4 + lg) ^ (lr & 7)) << 3)];
    #pragma unroll
    for (int td = 0; td < 2; ++td)
        #pragma unroll
        for (int kk = 0; kk < 2; ++kk)
            vf[td][kk] = *(const bf16x8*)&vts[(td * 16 + lr) * 64 +
                                              (((kk * 4 + lg) ^ (lr & 7)) << 3)];

    f32x4 o[4][2];
    #pragma unroll
    for (int a = 0; a < 4; ++a) { o[a][0] = f32x4{0.f,0.f,0.f,0.f}; o[a][1] = f32x4{0.f,0.f,0.f,0.f}; }
    #pragma unroll
    for (int kk = 0; kk < 2; ++kk)
        #pragma unroll
        for (int mi = 0; mi < 4; ++mi)
            #pragma unroll
            for (int td = 0; td < 2; ++td)
                o[mi][td] = __builtin_amdgcn_mfma_f32_16x16x32_bf16(
                    pa[mi][kk], vf[td][kk], o[mi][td], 0, 0, 0);

    bf16* op = outb + (size_t)window * 49 * 384 + head * 32;
    #pragma unroll
    for (int mi = 0; mi < 4; ++mi)
        #pragma unroll
        for (int r = 0; r < 4; ++r) {
            int i = mi * 16 + lg * 4 + r;
            if (i < 49) {
                #pragma unroll
                for (int td = 0; td < 2; ++td)
                    op[(size_t)i * 384 + td * 16 + lr] = (bf16)o[mi][td][r];
            }
        }
}

// ---------------------------------------------------------------- launch
extern "C" void kernel_launch(void* const* d_in, const int* in_sizes, int n_in,
                              void* d_out, int out_size, void* d_ws, size_t ws_size,
                              hipStream_t stream)
{
    const float* x     = (const float*)d_in[0];
    const float* n1g   = (const float*)d_in[1];
    const float* n1b   = (const float*)d_in[2];
    const float* qkvw  = (const float*)d_in[3];
    const float* qkvb  = (const float*)d_in[4];
    const float* rpb   = (const float*)d_in[5];
    const float* projw = (const float*)d_in[6];
    const float* projb = (const float*)d_in[7];
    const float* n2g   = (const float*)d_in[8];
    const float* n2b   = (const float*)d_in[9];
    const float* fc1w  = (const float*)d_in[10];
    const float* fc1b  = (const float*)d_in[11];
    const float* fc2w  = (const float*)d_in[12];
    const float* fc2b  = (const float*)d_in[13];
    float* out = (float*)d_out;

    char* ws = (char*)d_ws;
    bf16* Wq   = (bf16*)(ws);                 // all 4 weights contiguous bf16
    bf16* Wp   = (bf16*)(ws + 884736);
    bf16* W1   = (bf16*)(ws + 1179648);
    bf16* W2   = (bf16*)(ws + 2359296);
    bf16* ywin = (bf16*)(ws + 3538944);       // 100352*384 bf16
    bf16* qkv  = (bf16*)(ws + 80609280);      // 100352*1152 bf16
    bf16* attn = (bf16*)(ws + 311820288);     // 100352*384 bf16
    bf16* hbuf = (bf16*)(ws + 80609280);      // reuse qkv+attn after attention
    bf16* y2   = ywin;                        // reuse after qkv gemm
    float* fusedT = (float*)ws;               // 786KB over Wq (dead post-gemm0)

    k_cvtw<<<6912, 256, 0, stream>>>(qkvw, projw, fc1w, fc2w, Wq);
    k_ln1<<<25088, 256, 0, stream>>>(x, n1g, n1b, ywin);
    k_gemm<0><<<784 * 9, 256, 0, stream>>>(ywin, Wq, qkvb, nullptr, qkv, 1152, 384, 9);
    k_bias<<<48, 256, 0, stream>>>(rpb, fusedT);
    k_attn<<<6144, 256, 0, stream>>>(qkv, fusedT, attn);
    k_gemm<1><<<784 * 3, 256, 0, stream>>>(attn, Wp, projb, x, out, 384, 384, 3);
    k_ln2<<<25088, 256, 0, stream>>>(out, n2g, n2b, y2);
    k_gemm<2><<<784 * 12, 256, 0, stream>>>(y2, W1, fc1b, nullptr, hbuf, 1536, 384, 12);
    k_gemm<3><<<784 * 3, 256, 0, stream>>>(hbuf, W2, fc2b, nullptr, out, 384, 1536, 3);
}

// Round 5
// 1128.820 us; speedup vs baseline: 1.2264x; 1.0889x over previous
//
#include <hip/hip_runtime.h>
#include <cstdint>
#include <cstddef>

typedef __bf16 bf16;
typedef __bf16 bf16x8 __attribute__((ext_vector_type(8)));
typedef float f32x4 __attribute__((ext_vector_type(4)));
typedef unsigned int u32;

__device__ __forceinline__ u32 pk(float a, float b) {
    u32 ua = __builtin_bit_cast(unsigned short, (bf16)a);
    u32 ub = __builtin_bit_cast(unsigned short, (bf16)b);
    return (ub << 16) | ua;
}

// async global->LDS, 16B per lane; LDS dest = wave-uniform base + lane*16
__device__ __forceinline__ void gld16(void* l, const void* g) {
    __builtin_amdgcn_global_load_lds(
        (const __attribute__((address_space(1))) void*)(size_t)g,
        (__attribute__((address_space(3))) void*)l, 16, 0, 0);
}

// ---------------------------------------------------------------- weight cvt
__global__ __launch_bounds__(256) void k_cvtw(
    const float* __restrict__ w0, const float* __restrict__ w1,
    const float* __restrict__ w2, const float* __restrict__ w3,
    bf16* __restrict__ o)
{
    int i = blockIdx.x * 256 + threadIdx.x;
    float v;
    if (i < 442368)       v = w0[i];
    else if (i < 589824)  v = w1[i - 442368];
    else if (i < 1179648) v = w2[i - 589824];
    else                  v = w3[i - 1179648];
    o[i] = (bf16)v;
}

// ---------------------------------------------------------------- fused bias
// fusedT[type][head][i][j], type = (wh==7)*2 + (ww==7); log2e folded in.
__global__ __launch_bounds__(256) void k_bias(
    const float* __restrict__ rpb, float* __restrict__ ft)
{
    int t = blockIdx.x;                  // 0..47 = type*12+head
    int type = t / 12, head = t - (t / 12) * 12;
    for (int e = threadIdx.x; e < 4096; e += 256) {
        int i = e >> 6, j = e & 63;
        float v;
        if (j >= 49) v = -1e30f;
        else if (i >= 49) v = 0.f;
        else {
            int ri = i / 7, ci = i - ri * 7, rj = j / 7, cj = j - rj * 7;
            v = rpb[((ri - rj + 6) * 13 + (ci - cj + 6)) * 12 + head] * 1.4426950408889634f;
            int li = 0, lj = 0;
            if (type & 2) { li += (ri < 4) ? 3 : 6; lj += (rj < 4) ? 3 : 6; }
            if (type & 1) { li += (ci < 4) ? 1 : 2; lj += (cj < 4) ? 1 : 2; }
            if (li != lj) v -= 144.26950408889634f;   // -100 * log2e
        }
        ft[(size_t)t * 4096 + e] = v;
    }
}

// ---------------------------------------------------------------- layernorm
__global__ __launch_bounds__(256) void k_ln1(
    const float* __restrict__ x, const float* __restrict__ g,
    const float* __restrict__ b, bf16* __restrict__ ywin)
{
    int wv = threadIdx.x >> 6, lane = threadIdx.x & 63;
    int tok = blockIdx.x * 4 + wv;            // 0..100351
    const float2* xp = (const float2*)(x + (size_t)tok * 384);
    float2 v[3];
    float s = 0.f, ss = 0.f;
    #pragma unroll
    for (int j = 0; j < 3; ++j) {
        v[j] = xp[j * 64 + lane];
        s += v[j].x + v[j].y; ss += v[j].x * v[j].x + v[j].y * v[j].y;
    }
    #pragma unroll
    for (int o = 32; o; o >>= 1) { s += __shfl_xor(s, o); ss += __shfl_xor(ss, o); }
    float mean = s * (1.f / 384.f);
    float rstd = rsqrtf(ss * (1.f / 384.f) - mean * mean + 1e-5f);
    int bi = tok / 3136, l = tok - bi * 3136;
    int h = l / 56, w = l - h * 56;
    int hs = h + 53; if (hs >= 56) hs -= 56;  // (h-3) mod 56
    int ws = w + 53; if (ws >= 56) ws -= 56;
    int m = (bi * 64 + (hs / 7) * 8 + (ws / 7)) * 49 + (hs % 7) * 7 + (ws % 7);
    u32* op = (u32*)(ywin + (size_t)m * 384);
    const float2* g2 = (const float2*)g;
    const float2* b2 = (const float2*)b;
    #pragma unroll
    for (int j = 0; j < 3; ++j) {
        int c2 = j * 64 + lane;
        float2 gg = g2[c2], bb = b2[c2];
        op[c2] = pk((v[j].x - mean) * rstd * gg.x + bb.x,
                    (v[j].y - mean) * rstd * gg.y + bb.y);
    }
}

__global__ __launch_bounds__(256) void k_ln2(
    const float* __restrict__ x, const float* __restrict__ g,
    const float* __restrict__ b, bf16* __restrict__ y)
{
    int wv = threadIdx.x >> 6, lane = threadIdx.x & 63;
    int tok = blockIdx.x * 4 + wv;
    const float2* xp = (const float2*)(x + (size_t)tok * 384);
    float2 v[3];
    float s = 0.f, ss = 0.f;
    #pragma unroll
    for (int j = 0; j < 3; ++j) {
        v[j] = xp[j * 64 + lane];
        s += v[j].x + v[j].y; ss += v[j].x * v[j].x + v[j].y * v[j].y;
    }
    #pragma unroll
    for (int o = 32; o; o >>= 1) { s += __shfl_xor(s, o); ss += __shfl_xor(ss, o); }
    float mean = s * (1.f / 384.f);
    float rstd = rsqrtf(ss * (1.f / 384.f) - mean * mean + 1e-5f);
    u32* op = (u32*)(y + (size_t)tok * 384);
    const float2* g2 = (const float2*)g;
    const float2* b2 = (const float2*)b;
    #pragma unroll
    for (int j = 0; j < 3; ++j) {
        int c2 = j * 64 + lane;
        float2 gg = g2[c2], bb = b2[c2];
        op[c2] = pk((v[j].x - mean) * rstd * gg.x + bb.x,
                    (v[j].y - mean) * rstd * gg.y + bb.y);
    }
}

// ---------------------------------------------------------------- GEMM
// C[M,N] = A[M,K] * Bt[N,K]^T (+ epilogue). 128x128 tile, BK=32, 4 waves.
// T3+T4: 3-buffer LDS pipeline, 2 tiles prefetched, counted vmcnt (never 0
// in steady state), raw s_barrier. 4 gld16/wave/tile -> vmcnt(8) waits for
// the tile staged 2 iterations ago. Bias preloaded so the only VMEM ops in
// the loop window are the gld16s (vmcnt retires in-order; early bias loads
// drain first). Epilogue resid/out loads sit after the final vmcnt(0) fence.
// EPI: 0 = qkv (bias, fold q-scale*log2e, bf16 out)
//      1 = proj (bias + window-reverse + unshift + residual add, fp32 out)
//      2 = fc1 (bias + exact GELU, bf16 out)
//      3 = fc2 (bias + accumulate into fp32 out)
template<int EPI>
__global__ __launch_bounds__(256, 2) void k_gemm(
    const bf16* __restrict__ A, const bf16* __restrict__ Bt,
    const float* __restrict__ bias, const float* __restrict__ resid,
    void* __restrict__ out, int N, int K, int nbn)
{
    __shared__ bf16 As[3][128 * 32];
    __shared__ bf16 Bs[3][128 * 32];

    int nwg = gridDim.x;
    int bid = blockIdx.x;
    int swz = (bid & 7) * (nwg >> 3) + (bid >> 3);   // grids all %8==0
    int bm = swz / nbn, bn = swz % nbn;

    int tid  = threadIdx.x;
    int lane = tid & 63;
    int wv   = tid >> 6;
    int wr = wv >> 1, wc = wv & 1;
    int lr = lane & 15, lg = lane >> 4;

    // wave wv stages rows [32wv,32wv+32): LDS[row][slot] = G[row][slot^((row>>1)&3)]
    int rowL = wv * 32 + (lane >> 2);
    int seg  = (lane & 3) ^ ((rowL >> 1) & 3);
    const bf16* ga0 = A  + (size_t)(bm * 128 + rowL) * K + seg * 8;
    const bf16* gb0 = Bt + (size_t)(bn * 128 + rowL) * K + seg * 8;
    const bf16* ga1 = ga0 + (size_t)16 * K;
    const bf16* gb1 = gb0 + (size_t)16 * K;
    int lbase = wv * 32 * 32;

    int col0 = bn * 128 + wc * 64;
    float bv[4];
    #pragma unroll
    for (int ni = 0; ni < 4; ++ni) bv[ni] = bias[col0 + ni * 16 + lr];

    f32x4 acc[4][4] = {};

    auto STAGE = [&](int b, int k0) {
        gld16(&As[b][lbase],           ga0 + k0);
        gld16(&As[b][lbase + 16 * 32], ga1 + k0);
        gld16(&Bs[b][lbase],           gb0 + k0);
        gld16(&Bs[b][lbase + 16 * 32], gb1 + k0);
    };
    auto COMPUTE = [&](int b) {
        const bf16* cA = As[b];
        const bf16* cB = Bs[b];
        bf16x8 af[4], bfr[4];
        #pragma unroll
        for (int i = 0; i < 4; ++i) {
            int ra = wr * 64 + i * 16 + lr;
            af[i]  = *(const bf16x8*)&cA[ra * 32 + ((lg ^ ((ra >> 1) & 3)) << 3)];
            int rb = wc * 64 + i * 16 + lr;
            bfr[i] = *(const bf16x8*)&cB[rb * 32 + ((lg ^ ((rb >> 1) & 3)) << 3)];
        }
        __builtin_amdgcn_s_setprio(1);
        #pragma unroll
        for (int mi = 0; mi < 4; ++mi)
            #pragma unroll
            for (int ni = 0; ni < 4; ++ni)
                acc[mi][ni] = __builtin_amdgcn_mfma_f32_16x16x32_bf16(
                    af[mi], bfr[ni], acc[mi][ni], 0, 0, 0);
        __builtin_amdgcn_s_setprio(0);
    };

    STAGE(0, 0);
    STAGE(1, 32);                       // K >= 64 always (384 / 1536)
    int cur = 0;
    int k0 = 0;
    for (; k0 + 64 < K; k0 += 32) {
        int nb = cur + 2; if (nb >= 3) nb -= 3;
        STAGE(nb, k0 + 64);
        __builtin_amdgcn_sched_barrier(0);
        asm volatile("s_waitcnt vmcnt(8)" ::: "memory");   // tile t landed
        __builtin_amdgcn_sched_barrier(0);
        __builtin_amdgcn_s_barrier();
        COMPUTE(cur);
        __builtin_amdgcn_s_barrier();   // all reads of buf[cur] done
        cur = (cur + 1 == 3) ? 0 : cur + 1;
    }
    // tile nt-2: only tile nt-1's 4 loads may remain outstanding
    asm volatile("s_waitcnt vmcnt(4)" ::: "memory");
    __builtin_amdgcn_sched_barrier(0);
    __builtin_amdgcn_s_barrier();
    COMPUTE(cur);
    __builtin_amdgcn_s_barrier();
    cur = (cur + 1 == 3) ? 0 : cur + 1;
    // tile nt-1
    asm volatile("s_waitcnt vmcnt(0)" ::: "memory");
    __builtin_amdgcn_sched_barrier(0);
    __builtin_amdgcn_s_barrier();
    COMPUTE(cur);

    int row0 = bm * 128 + wr * 64;
    #pragma unroll
    for (int mi = 0; mi < 4; ++mi)
    #pragma unroll
    for (int ni = 0; ni < 4; ++ni)
    #pragma unroll
    for (int r = 0; r < 4; ++r) {
        int gr = row0 + mi * 16 + lg * 4 + r;   // C/D: row=(lane>>4)*4+reg
        int gc = col0 + ni * 16 + lr;           //      col=lane&15
        float v = acc[mi][ni][r] + bv[ni];
        if constexpr (EPI == 0) {
            if (gc < 384) v *= 0.25498226244716875f;   // d^-0.5 * log2(e)
            ((bf16*)out)[(size_t)gr * N + gc] = (bf16)v;
        } else if constexpr (EPI == 1) {
            int bi = gr / 3136, rem = gr - bi * 3136;
            int win = rem / 49, pos = rem - win * 49;
            int hs = (win >> 3) * 7 + pos / 7;
            int ws = (win & 7) * 7 + pos % 7;
            hs += 3; if (hs >= 56) hs -= 56;   // reverse shift
            ws += 3; if (ws >= 56) ws -= 56;
            size_t oi = ((size_t)bi * 3136 + hs * 56 + ws) * 384 + gc;
            ((float*)out)[oi] = resid[oi] + v;
        } else if constexpr (EPI == 2) {
            float ge = 0.5f * v * (1.f + erff(v * 0.70710678118654752f));
            ((bf16*)out)[(size_t)gr * N + gc] = (bf16)ge;
        } else {
            size_t oi = (size_t)gr * 384 + gc;
            ((float*)out)[oi] += v;
        }
    }
}

// ---------------------------------------------------------------- attention
// 4 waves/block = 4 heads of one window (unchanged from round 3).
__global__ __launch_bounds__(256, 3) void k_attn(
    const bf16* __restrict__ qkv, const float* __restrict__ fusedT,
    bf16* __restrict__ outb)
{
    __shared__ bf16 vt[4][32 * 64];
    __shared__ bf16 pl[4][64 * 64];

    int bid = blockIdx.x;
    int swz = (bid & 7) * (6144 >> 3) + (bid >> 3);
    int window = swz / 3;
    int wv = threadIdx.x >> 6, lane = threadIdx.x & 63;
    int head = (swz - window * 3) * 4 + wv;
    int lr = lane & 15, lg = lane >> 4;

    size_t base = (size_t)window * 49 * 1152 + head * 32;
    const bf16* Qp = qkv + base;
    const bf16* Kp = qkv + base + 384;
    const bf16* Vp = qkv + base + 768;

    bf16* vts = vt[wv];
    #pragma unroll
    for (int t0 = 0; t0 < 8; ++t0) {
        int t = t0 * 64 + lane;            // 512 tasks: d x pos(48..63)
        int d = t >> 4, pos = 48 + (t & 15);
        vts[d * 64 + ((((pos >> 3) ^ (d & 7)) << 3) | (pos & 7))] = (bf16)0.f;
    }
    #pragma unroll
    for (int t0 = 0; t0 < 4; ++t0) {
        int t = t0 * 64 + lane;            // 196 tasks: pos x 4 d-chunks
        if (t < 196) {
            int pos = t >> 2, c8 = (t & 3) << 3;
            bf16x8 vv = *(const bf16x8*)(Vp + (size_t)pos * 1152 + c8);
            #pragma unroll
            for (int u = 0; u < 8; ++u) {
                int d = c8 + u;
                vts[d * 64 + ((((pos >> 3) ^ (d & 7)) << 3) | (pos & 7))] = vv[u];
            }
        }
    }

    bf16x8 kf[4], qf[4];
    #pragma unroll
    for (int t = 0; t < 4; ++t) {
        int row = t * 16 + lr; row = row > 48 ? 48 : row;
        kf[t] = *(const bf16x8*)(Kp + (size_t)row * 1152 + lg * 8);
        qf[t] = *(const bf16x8*)(Qp + (size_t)row * 1152 + lg * 8);
    }
    f32x4 st[4][4];
    #pragma unroll
    for (int a = 0; a < 4; ++a)
        #pragma unroll
        for (int c = 0; c < 4; ++c) st[a][c] = f32x4{0.f, 0.f, 0.f, 0.f};
    #pragma unroll
    for (int mj = 0; mj < 4; ++mj)
        #pragma unroll
        for (int ni = 0; ni < 4; ++ni)
            st[mj][ni] = __builtin_amdgcn_mfma_f32_16x16x32_bf16(
                kf[mj], qf[ni], st[mj][ni], 0, 0, 0);

    int wtype = (((window & 63) >= 56) ? 2 : 0) | (((window & 7) == 7) ? 1 : 0);
    const float* bt = fusedT + ((size_t)(wtype * 12 + head) << 12);
    #pragma unroll
    for (int ni = 0; ni < 4; ++ni)
        #pragma unroll
        for (int mj = 0; mj < 4; ++mj) {
            f32x4 bv = *(const f32x4*)(bt + (ni * 16 + lr) * 64 + mj * 16 + lg * 4);
            st[mj][ni] += bv;
        }

    #pragma unroll
    for (int ni = 0; ni < 4; ++ni) {
        float mx = -1e30f;
        #pragma unroll
        for (int mj = 0; mj < 4; ++mj)
            mx = fmaxf(mx, fmaxf(fmaxf(st[mj][ni][0], st[mj][ni][1]),
                                 fmaxf(st[mj][ni][2], st[mj][ni][3])));
        mx = fmaxf(mx, __shfl_xor(mx, 16));
        mx = fmaxf(mx, __shfl_xor(mx, 32));
        float l = 0.f;
        #pragma unroll
        for (int mj = 0; mj < 4; ++mj)
            #pragma unroll
            for (int r = 0; r < 4; ++r) {
                float p = exp2f(st[mj][ni][r] - mx);
                st[mj][ni][r] = p; l += p;
            }
        l += __shfl_xor(l, 16);
        l += __shfl_xor(l, 32);
        float rl = 1.f / l;
        #pragma unroll
        for (int mj = 0; mj < 4; ++mj)
            #pragma unroll
            for (int r = 0; r < 4; ++r) st[mj][ni][r] *= rl;
    }

    bf16* plw = pl[wv];
    #pragma unroll
    for (int mj = 0; mj < 4; ++mj)
        #pragma unroll
        for (int ni = 0; ni < 4; ++ni)
            #pragma unroll
            for (int hh = 0; hh < 2; ++hh) {
                u32 w = pk(st[mj][ni][hh * 2], st[mj][ni][hh * 2 + 1]);
                int j = mj * 16 + lg * 4 + hh * 2;
                int i = ni * 16 + lr;
                *(u32*)&plw[i * 64 + (((j >> 3) ^ (lr & 7)) << 3) + (j & 7)] = w;
            }

    bf16x8 pa[4][2], vf[2][2];
    #pragma unroll
    for (int mi = 0; mi < 4; ++mi)
        #pragma unroll
        for (int kk = 0; kk < 2; ++kk)
            pa[mi][kk] = *(const bf16x8*)&plw[(mi * 16 + lr) * 64 +
                                              (((kk * 4 + lg) ^ (lr & 7)) << 3)];
    #pragma unroll
    for (int td = 0; td < 2; ++td)
        #pragma unroll
        for (int kk = 0; kk < 2; ++kk)
            vf[td][kk] = *(const bf16x8*)&vts[(td * 16 + lr) * 64 +
                                              (((kk * 4 + lg) ^ (lr & 7)) << 3)];

    f32x4 o[4][2];
    #pragma unroll
    for (int a = 0; a < 4; ++a) { o[a][0] = f32x4{0.f,0.f,0.f,0.f}; o[a][1] = f32x4{0.f,0.f,0.f,0.f}; }
    #pragma unroll
    for (int kk = 0; kk < 2; ++kk)
        #pragma unroll
        for (int mi = 0; mi < 4; ++mi)
            #pragma unroll
            for (int td = 0; td < 2; ++td)
                o[mi][td] = __builtin_amdgcn_mfma_f32_16x16x32_bf16(
                    pa[mi][kk], vf[td][kk], o[mi][td], 0, 0, 0);

    bf16* op = outb + (size_t)window * 49 * 384 + head * 32;
    #pragma unroll
    for (int mi = 0; mi < 4; ++mi)
        #pragma unroll
        for (int r = 0; r < 4; ++r) {
            int i = mi * 16 + lg * 4 + r;
            if (i < 49) {
                #pragma unroll
                for (int td = 0; td < 2; ++td)
                    op[(size_t)i * 384 + td * 16 + lr] = (bf16)o[mi][td][r];
            }
        }
}

// ---------------------------------------------------------------- launch
extern "C" void kernel_launch(void* const* d_in, const int* in_sizes, int n_in,
                              void* d_out, int out_size, void* d_ws, size_t ws_size,
                              hipStream_t stream)
{
    const float* x     = (const float*)d_in[0];
    const float* n1g   = (const float*)d_in[1];
    const float* n1b   = (const float*)d_in[2];
    const float* qkvw  = (const float*)d_in[3];
    const float* qkvb  = (const float*)d_in[4];
    const float* rpb   = (const float*)d_in[5];
    const float* projw = (const float*)d_in[6];
    const float* projb = (const float*)d_in[7];
    const float* n2g   = (const float*)d_in[8];
    const float* n2b   = (const float*)d_in[9];
    const float* fc1w  = (const float*)d_in[10];
    const float* fc1b  = (const float*)d_in[11];
    const float* fc2w  = (const float*)d_in[12];
    const float* fc2b  = (const float*)d_in[13];
    float* out = (float*)d_out;

    char* ws = (char*)d_ws;
    bf16* Wq   = (bf16*)(ws);                 // all 4 weights contiguous bf16
    bf16* Wp   = (bf16*)(ws + 884736);
    bf16* W1   = (bf16*)(ws + 1179648);
    bf16* W2   = (bf16*)(ws + 2359296);
    bf16* ywin = (bf16*)(ws + 3538944);       // 100352*384 bf16
    bf16* qkv  = (bf16*)(ws + 80609280);      // 100352*1152 bf16
    bf16* attn = (bf16*)(ws + 311820288);     // 100352*384 bf16
    bf16* hbuf = (bf16*)(ws + 80609280);      // reuse qkv+attn after attention
    bf16* y2   = ywin;                        // reuse after qkv gemm
    float* fusedT = (float*)ws;               // 786KB over Wq (dead post-gemm0)

    k_cvtw<<<6912, 256, 0, stream>>>(qkvw, projw, fc1w, fc2w, Wq);
    k_ln1<<<25088, 256, 0, stream>>>(x, n1g, n1b, ywin);
    k_gemm<0><<<784 * 9, 256, 0, stream>>>(ywin, Wq, qkvb, nullptr, qkv, 1152, 384, 9);
    k_bias<<<48, 256, 0, stream>>>(rpb, fusedT);
    k_attn<<<6144, 256, 0, stream>>>(qkv, fusedT, attn);
    k_gemm<1><<<784 * 3, 256, 0, stream>>>(attn, Wp, projb, x, out, 384, 384, 3);
    k_ln2<<<25088, 256, 0, stream>>>(out, n2g, n2b, y2);
    k_gemm<2><<<784 * 12, 256, 0, stream>>>(y2, W1, fc1b, nullptr, hbuf, 1536, 384, 12);
    k_gemm<3><<<784 * 3, 256, 0, stream>>>(hbuf, W2, fc2b, nullptr, out, 384, 1536, 3);
}